// Round 1
// baseline (2019.476 us; speedup 1.0000x reference)
//
#include <hip/hip_runtime.h>
#include <math.h>

#define HWN 65536

__device__ __forceinline__ float sgm(float x){ return 1.0f/(1.0f+expf(-x)); }

__device__ __forceinline__ void fma4(float acc[4], const float4 w,
                                     const float4 x0, const float4 x1,
                                     const float4 x2, const float4 x3){
    acc[0] += w.x*x0.x + w.y*x1.x + w.z*x2.x + w.w*x3.x;
    acc[1] += w.x*x0.y + w.y*x1.y + w.z*x2.y + w.w*x3.y;
    acc[2] += w.x*x0.z + w.y*x1.z + w.z*x2.z + w.w*x3.z;
    acc[3] += w.x*x0.w + w.y*x1.w + w.z*x2.w + w.w*x3.w;
}

// ---------------------------------------------------------------------------
// K1: input_proj + lb store + lgce_pre (+pooled partials) + qkv + gate scalar
// block = 256 threads, 64 pixels; LDS: x tile 32KB + proj tile 32KB
// ---------------------------------------------------------------------------
__global__ __launch_bounds__(256,2) void k1_proj(
    const float* __restrict__ x,   const float* __restrict__ Wp,
    const float* __restrict__ Wpre,const float* __restrict__ bpre,
    const float* __restrict__ Wqkv,
    const float* __restrict__ Wg1, const float* __restrict__ bg1,
    const float* __restrict__ wg2, const float* __restrict__ bg2,
    float* __restrict__ lb, float* __restrict__ pre, float* __restrict__ qkv,
    float* __restrict__ pooled_part, float* __restrict__ gate_part)
{
    __shared__ float xt[128*64];
    __shared__ float pt[128*64];
    float* ht = xt;                       // reused after proj phase
    float4* xt4 = (float4*)xt;
    float4* pt4 = (float4*)pt;

    const int t    = threadIdx.x;
    const int blk  = blockIdx.x;
    const int b    = blk >> 10;           // 1024 blocks per batch
    const int p0   = (blk & 1023) << 6;   // 64 px / block
    const int pg   = t & 15;              // pixel group (4 px)
    const int og   = t >> 4;              // output group
    const int slot = blk & 63;

    // load x tile [128][64] as float4
    const float4* x4 = (const float4*)x;
    #pragma unroll
    for (int i = 0; i < 8; ++i) {
        int idx = t + 256*i;
        int c = idx >> 4, q = idx & 15;
        xt4[c*16 + q] = x4[(size_t)(b*128 + c)*16384 + (p0>>2) + q];
    }
    __syncthreads();

    // ---- proj: o = og*8..+7, px = pg*4..+3
    {
        const int o0 = og*8;
        float acc[8][4];
        #pragma unroll
        for (int j=0;j<8;++j){acc[j][0]=0.f;acc[j][1]=0.f;acc[j][2]=0.f;acc[j][3]=0.f;}
        const float4* W4 = (const float4*)Wp;
        for (int c = 0; c < 128; c += 4) {
            float4 x0 = xt4[(c+0)*16+pg];
            float4 x1 = xt4[(c+1)*16+pg];
            float4 x2 = xt4[(c+2)*16+pg];
            float4 x3 = xt4[(c+3)*16+pg];
            #pragma unroll
            for (int j=0;j<8;++j)
                fma4(acc[j], W4[(o0+j)*32 + (c>>2)], x0,x1,x2,x3);
        }
        #pragma unroll
        for (int j=0;j<8;++j)
            pt4[(o0+j)*16+pg] = make_float4(acc[j][0],acc[j][1],acc[j][2],acc[j][3]);
    }
    __syncthreads();

    // ---- lb (proj rows 0..63) to global
    {
        float4* lb4 = (float4*)lb;
        #pragma unroll
        for (int i=0;i<4;++i){
            int idx = t + 256*i;
            int c = idx >> 4, q = idx & 15;
            lb4[(size_t)(b*64 + c)*16384 + (p0>>2) + q] = pt4[c*16+q];
        }
    }

    // ---- pre conv (64x64) + pooled partial sums
    {
        const int o0 = og*4;
        float acc[4][4];
        #pragma unroll
        for (int j=0;j<4;++j){acc[j][0]=0.f;acc[j][1]=0.f;acc[j][2]=0.f;acc[j][3]=0.f;}
        const float4* W4 = (const float4*)Wpre;
        for (int c = 0; c < 64; c += 4) {
            float4 x0 = pt4[(c+0)*16+pg];
            float4 x1 = pt4[(c+1)*16+pg];
            float4 x2 = pt4[(c+2)*16+pg];
            float4 x3 = pt4[(c+3)*16+pg];
            #pragma unroll
            for (int j=0;j<4;++j)
                fma4(acc[j], W4[(o0+j)*16 + (c>>2)], x0,x1,x2,x3);
        }
        float4* pre4 = (float4*)pre;
        #pragma unroll
        for (int j=0;j<4;++j){
            float bs = bpre[o0+j];
            float4 vv = make_float4(acc[j][0]+bs, acc[j][1]+bs, acc[j][2]+bs, acc[j][3]+bs);
            pre4[(size_t)(b*64 + o0+j)*16384 + (p0>>2) + pg] = vv;
            float s = vv.x+vv.y+vv.z+vv.w;
            s += __shfl_xor(s,1); s += __shfl_xor(s,2);
            s += __shfl_xor(s,4); s += __shfl_xor(s,8);
            if (pg == 0) atomicAdd(&pooled_part[slot*256 + b*64 + o0 + j], s);
        }
    }

    // ---- qkv conv (192x64)
    {
        const int o0 = og*12;
        float acc[12][4];
        #pragma unroll
        for (int j=0;j<12;++j){acc[j][0]=0.f;acc[j][1]=0.f;acc[j][2]=0.f;acc[j][3]=0.f;}
        const float4* W4 = (const float4*)Wqkv;
        for (int c = 0; c < 64; c += 4) {
            float4 x0 = pt4[(64+c+0)*16+pg];
            float4 x1 = pt4[(64+c+1)*16+pg];
            float4 x2 = pt4[(64+c+2)*16+pg];
            float4 x3 = pt4[(64+c+3)*16+pg];
            #pragma unroll
            for (int j=0;j<12;++j)
                fma4(acc[j], W4[(o0+j)*16 + (c>>2)], x0,x1,x2,x3);
        }
        float4* qkv4 = (float4*)qkv;
        #pragma unroll
        for (int j=0;j<12;++j)
            qkv4[(size_t)(b*192 + o0+j)*16384 + (p0>>2) + pg] =
                make_float4(acc[j][0],acc[j][1],acc[j][2],acc[j][3]);
    }

    // ---- gate hidden (32x64) -> ht
    {
        const int o0 = og*2;
        float acc[2][4];
        #pragma unroll
        for (int j=0;j<2;++j){acc[j][0]=0.f;acc[j][1]=0.f;acc[j][2]=0.f;acc[j][3]=0.f;}
        const float4* W4 = (const float4*)Wg1;
        for (int c = 0; c < 64; c += 4) {
            float4 x0 = pt4[(64+c+0)*16+pg];
            float4 x1 = pt4[(64+c+1)*16+pg];
            float4 x2 = pt4[(64+c+2)*16+pg];
            float4 x3 = pt4[(64+c+3)*16+pg];
            #pragma unroll
            for (int j=0;j<2;++j)
                fma4(acc[j], W4[(o0+j)*16 + (c>>2)], x0,x1,x2,x3);
        }
        #pragma unroll
        for (int j=0;j<2;++j){
            float bs = bg1[o0+j];
            #pragma unroll
            for (int k=0;k<4;++k)
                ht[(o0+j)*64 + pg*4 + k] = fmaxf(acc[j][k]+bs, 0.0f);
        }
    }
    __syncthreads();

    // ---- gate scalar per pixel + partial sum
    if (t < 64) {
        float g = bg2[0];
        #pragma unroll
        for (int c = 0; c < 32; ++c) g += wg2[c]*ht[c*64 + t];
        g = sgm(g);
        g += __shfl_xor(g,1);  g += __shfl_xor(g,2);  g += __shfl_xor(g,4);
        g += __shfl_xor(g,8);  g += __shfl_xor(g,16); g += __shfl_xor(g,32);
        if (t == 0) atomicAdd(&gate_part[slot], g);
    }
}

// ---------------------------------------------------------------------------
// K2: pooled -> cw (CBAM channel MLP), gate mean -> kdyn. single block.
// ---------------------------------------------------------------------------
__global__ void k2_small(const float* __restrict__ pooled_part,
                         const float* __restrict__ gate_part,
                         const float* __restrict__ w1, const float* __restrict__ b1,
                         const float* __restrict__ w2, const float* __restrict__ b2,
                         float* __restrict__ cw, float* __restrict__ kdyn)
{
    __shared__ float pl[256];
    const int t = threadIdx.x;
    float s = 0.f;
    for (int sl = 0; sl < 64; ++sl) s += pooled_part[sl*256 + t];
    pl[t] = s * (1.0f/65536.0f);
    __syncthreads();
    const int b = t >> 6, g = (t >> 3) & 7, c = t & 7;
    float h0 = b1[g*2+0], h1 = b1[g*2+1];
    #pragma unroll
    for (int cc = 0; cc < 8; ++cc) {
        float p = pl[b*64 + g*8 + cc];
        h0 += p*w1[g*16 + 0*8 + cc];
        h1 += p*w1[g*16 + 1*8 + cc];
    }
    h0 = fmaxf(h0, 0.f); h1 = fmaxf(h1, 0.f);
    cw[t] = sgm(h0*w2[g*16 + c*2 + 0] + h1*w2[g*16 + c*2 + 1] + b2[g*8+c]);
    if (t == 0) {
        float gs = 0.f;
        for (int sl = 0; sl < 64; ++sl) gs += gate_part[sl];
        float kd = floorf(8.0f * (gs * (1.0f/262144.0f)));
        *kdyn = fminf(fmaxf(kd, 1.0f), 8.0f);
    }
}

// ---------------------------------------------------------------------------
// K3: resp partial sums for thr. 1024 blocks x 256 threads (1 px/thread).
// ---------------------------------------------------------------------------
__global__ __launch_bounds__(256) void k3_thr(
    const float* __restrict__ pre, const float* __restrict__ cw,
    const float* __restrict__ sw,  const float* __restrict__ sb,
    float* __restrict__ thr_sum)
{
    __shared__ float part[4][8];
    const int t = threadIdx.x;
    const int b = blockIdx.x >> 8;
    const int p = ((blockIdx.x & 255) << 8) + t;
    float rs[8];
    #pragma unroll
    for (int g = 0; g < 8; ++g) {
        float xc[8];
        float spa = sb[g];
        #pragma unroll
        for (int c = 0; c < 8; ++c) {
            float xv = pre[(size_t)(b*64 + g*8 + c)*HWN + p];
            xc[c] = xv * cw[b*64 + g*8 + c];
            spa += xc[c]*sw[g*8 + c];
        }
        float sp = sgm(spa);
        float s = 0.f;
        #pragma unroll
        for (int c = 0; c < 8; ++c) s += sgm(xc[c]*sp);
        rs[g] = s;
    }
    const int lane = t & 63, wv = t >> 6;
    #pragma unroll
    for (int g = 0; g < 8; ++g) {
        float val = rs[g];
        val += __shfl_xor(val,1);  val += __shfl_xor(val,2);  val += __shfl_xor(val,4);
        val += __shfl_xor(val,8);  val += __shfl_xor(val,16); val += __shfl_xor(val,32);
        if (lane == 0) part[wv][g] = val;
    }
    __syncthreads();
    if (t < 8)
        atomicAdd(&thr_sum[b*8 + t], part[0][t]+part[1][t]+part[2][t]+part[3][t]);
}

// ---------------------------------------------------------------------------
// K4: depthwise 3x3 over qkv; writes v only; accumulates q.k gram + sumsq.
// grid = B*8heads*64 blocks; each block does 4 16x16 tiles of its (b,h).
// ---------------------------------------------------------------------------
__device__ __forceinline__ float dw3x3(const float* sh, int ly, int lx,
                                       const float* __restrict__ wd){
    float r = 0.f;
    #pragma unroll
    for (int dy = 0; dy < 3; ++dy)
        #pragma unroll
        for (int dx = 0; dx < 3; ++dx)
            r += sh[(ly+dy)*20 + (lx+dx)] * wd[dy*3+dx];
    return r;
}

__global__ __launch_bounds__(256) void k4_dw(
    const float* __restrict__ qkv, const float* __restrict__ dww,
    float* __restrict__ v, float* __restrict__ Sg, float* __restrict__ sumsq)
{
    __shared__ float sh[8*360];
    const int t  = threadIdx.x;
    const int b  = blockIdx.x >> 9;
    const int h  = (blockIdx.x >> 6) & 7;
    const int tb = blockIdx.x & 63;
    const int ly = t >> 4, lx = t & 15;

    float S[64];
    #pragma unroll
    for (int i = 0; i < 64; ++i) S[i] = 0.f;
    float sq[8], sk[8];
    #pragma unroll
    for (int i = 0; i < 8; ++i) { sq[i]=0.f; sk[i]=0.f; }

    for (int rep = 0; rep < 4; ++rep) {
        const int tileIdx = tb*4 + rep;
        const int ty0 = (tileIdx >> 4) << 4;
        const int tx0 = (tileIdx & 15) << 4;
        float dq[8], dk[8];

        // q group
        __syncthreads();
        #pragma unroll
        for (int cc = 0; cc < 8; ++cc) {
            const float* base = qkv + (size_t)(b*192 + h*8 + cc)*HWN;
            for (int i = t; i < 324; i += 256) {
                int hy = i / 18, hx = i - hy*18;
                int gy = ty0 - 1 + hy, gx = tx0 - 1 + hx;
                float val = 0.f;
                if (gy >= 0 && gy < 256 && gx >= 0 && gx < 256) val = base[gy*256 + gx];
                sh[cc*360 + hy*20 + hx] = val;
            }
        }
        __syncthreads();
        #pragma unroll
        for (int cc = 0; cc < 8; ++cc)
            dq[cc] = dw3x3(sh + cc*360, ly, lx, dww + (h*8+cc)*9);

        // k group
        __syncthreads();
        #pragma unroll
        for (int cc = 0; cc < 8; ++cc) {
            const float* base = qkv + (size_t)(b*192 + 64 + h*8 + cc)*HWN;
            for (int i = t; i < 324; i += 256) {
                int hy = i / 18, hx = i - hy*18;
                int gy = ty0 - 1 + hy, gx = tx0 - 1 + hx;
                float val = 0.f;
                if (gy >= 0 && gy < 256 && gx >= 0 && gx < 256) val = base[gy*256 + gx];
                sh[cc*360 + hy*20 + hx] = val;
            }
        }
        __syncthreads();
        #pragma unroll
        for (int cc = 0; cc < 8; ++cc)
            dk[cc] = dw3x3(sh + cc*360, ly, lx, dww + (64+h*8+cc)*9);

        #pragma unroll
        for (int c = 0; c < 8; ++c) {
            sq[c] += dq[c]*dq[c];
            sk[c] += dk[c]*dk[c];
            #pragma unroll
            for (int d = 0; d < 8; ++d) S[c*8+d] += dq[c]*dk[d];
        }

        // v group
        __syncthreads();
        #pragma unroll
        for (int cc = 0; cc < 8; ++cc) {
            const float* base = qkv + (size_t)(b*192 + 128 + h*8 + cc)*HWN;
            for (int i = t; i < 324; i += 256) {
                int hy = i / 18, hx = i - hy*18;
                int gy = ty0 - 1 + hy, gx = tx0 - 1 + hx;
                float val = 0.f;
                if (gy >= 0 && gy < 256 && gx >= 0 && gx < 256) val = base[gy*256 + gx];
                sh[cc*360 + hy*20 + hx] = val;
            }
        }
        __syncthreads();
        {
            const int y = ty0 + ly, xx = tx0 + lx;
            #pragma unroll
            for (int cc = 0; cc < 8; ++cc) {
                float dv = dw3x3(sh + cc*360, ly, lx, dww + (128+h*8+cc)*9);
                v[(size_t)(b*64 + h*8 + cc)*HWN + y*256 + xx] = dv;
            }
        }
    }

    const int lane = t & 63;
    #pragma unroll
    for (int i = 0; i < 64; ++i) {
        float val = S[i];
        val += __shfl_xor(val,1);  val += __shfl_xor(val,2);  val += __shfl_xor(val,4);
        val += __shfl_xor(val,8);  val += __shfl_xor(val,16); val += __shfl_xor(val,32);
        if (lane == 0) atomicAdd(&Sg[(b*8+h)*64 + i], val);
    }
    #pragma unroll
    for (int i = 0; i < 8; ++i) {
        float v1 = sq[i], v2 = sk[i];
        v1 += __shfl_xor(v1,1);  v1 += __shfl_xor(v1,2);  v1 += __shfl_xor(v1,4);
        v1 += __shfl_xor(v1,8);  v1 += __shfl_xor(v1,16); v1 += __shfl_xor(v1,32);
        v2 += __shfl_xor(v2,1);  v2 += __shfl_xor(v2,2);  v2 += __shfl_xor(v2,4);
        v2 += __shfl_xor(v2,8);  v2 += __shfl_xor(v2,16); v2 += __shfl_xor(v2,32);
        if (lane == 0) {
            atomicAdd(&sumsq[b*128 + h*8 + i], v1);
            atomicAdd(&sumsq[b*128 + 64 + h*8 + i], v2);
        }
    }
}

// ---------------------------------------------------------------------------
// K6: finalize attention weights (norms, temp, rank top-k, softmax, scales)
// and thr. single block, thread=(b,h,c).
// ---------------------------------------------------------------------------
__global__ void k6_attn(const float* __restrict__ Sg, const float* __restrict__ sumsq,
                        const float* __restrict__ temp, const float* __restrict__ kdynp,
                        const float* __restrict__ thr_sum, const float* __restrict__ scales,
                        float* __restrict__ A, float* __restrict__ thr)
{
    const int t = threadIdx.x;
    if (t < 32) thr[t] = thr_sum[t] * (1.0f/(8.0f*65536.0f));
    const int b = t >> 6, h = (t >> 3) & 7, c = t & 7;
    const float kd = *kdynp;
    const float ssum = scales[0]+scales[1]+scales[2]+scales[3];
    const float nq = fmaxf(sqrtf(sumsq[b*128 + h*8 + c]), 1e-12f);
    const float tv = temp[h];
    const float* Srow = Sg + (size_t)(b*8+h)*64 + c*8;
    float a[8];
    #pragma unroll
    for (int d = 0; d < 8; ++d) {
        float nk = fmaxf(sqrtf(sumsq[b*128 + 64 + h*8 + d]), 1e-12f);
        a[d] = Srow[d] / (nq*nk) * tv;
    }
    bool keep[8];
    #pragma unroll
    for (int d = 0; d < 8; ++d) {
        int r = 0;
        #pragma unroll
        for (int e = 0; e < 8; ++e)
            r += (a[e] > a[d]) || (a[e] == a[d] && e < d);
        keep[d] = ((float)r < kd);
    }
    float m = -INFINITY;
    #pragma unroll
    for (int d = 0; d < 8; ++d) if (keep[d]) m = fmaxf(m, a[d]);
    float ex[8]; float sum = 0.f;
    #pragma unroll
    for (int d = 0; d < 8; ++d) { ex[d] = keep[d] ? expf(a[d]-m) : 0.f; sum += ex[d]; }
    const float inv = ssum / sum;
    #pragma unroll
    for (int d = 0; d < 8; ++d)
        A[(size_t)(b*8+h)*64 + c*8 + d] = ex[d]*inv;
}

// ---------------------------------------------------------------------------
// K7: mask path + post conv + residual + attn@v + proj_out, fused epilogue.
// block = 256 threads, 64 px; LDS: pre 16KB + v 16KB + fused 32KB
// ---------------------------------------------------------------------------
__global__ __launch_bounds__(256,2) void k7_final(
    const float* __restrict__ pre, const float* __restrict__ lb, const float* __restrict__ v,
    const float* __restrict__ cw,  const float* __restrict__ thr,
    const float* __restrict__ sw,  const float* __restrict__ sb,
    const float* __restrict__ A,
    const float* __restrict__ Wpost, const float* __restrict__ bpost,
    const float* __restrict__ Wout,  float* __restrict__ out)
{
    __shared__ float pr[64*64];
    __shared__ float vt[64*64];
    __shared__ float ft[128*64];
    float4* pr4 = (float4*)pr;
    float4* vt4 = (float4*)vt;
    float4* ft4 = (float4*)ft;

    const int t   = threadIdx.x;
    const int blk = blockIdx.x;
    const int b   = blk >> 10;
    const int p0  = (blk & 1023) << 6;
    const int pg  = t & 15;
    const int og  = t >> 4;

    const float4* pre4g = (const float4*)pre;
    const float4* v4g   = (const float4*)v;
    #pragma unroll
    for (int i = 0; i < 4; ++i) {
        int idx = t + 256*i;
        int c = idx >> 4, q = idx & 15;
        size_t gi = (size_t)(b*64 + c)*16384 + (p0>>2) + q;
        pr4[c*16+q] = pre4g[gi];
        vt4[c*16+q] = v4g[gi];
    }
    __syncthreads();

    // ---- mask path (in-place on pr): 2 tasks of (g, px) per thread
    #pragma unroll
    for (int s = 0; s < 2; ++s) {
        int task = t + 256*s;
        int g = task >> 6, px = task & 63;
        float xc[8], xv[8];
        float spa = sb[g];
        #pragma unroll
        for (int c = 0; c < 8; ++c) {
            xv[c] = pr[(g*8+c)*64 + px];
            xc[c] = xv[c]*cw[b*64 + g*8 + c];
            spa += xc[c]*sw[g*8 + c];
        }
        float sp = sgm(spa);
        float th = thr[b*8 + g];
        #pragma unroll
        for (int c = 0; c < 8; ++c) {
            float resp = sgm(xc[c]*sp);
            float mask = resp > th ? 1.0f : resp;
            pr[(g*8+c)*64 + px] = xv[c]*mask;
        }
    }
    __syncthreads();

    // ---- post conv (64x64) + bias + residual -> ft rows 64..127
    {
        const int o0 = og*4;
        float acc[4][4];
        #pragma unroll
        for (int j=0;j<4;++j){acc[j][0]=0.f;acc[j][1]=0.f;acc[j][2]=0.f;acc[j][3]=0.f;}
        const float4* W4 = (const float4*)Wpost;
        for (int c = 0; c < 64; c += 4) {
            float4 x0 = pr4[(c+0)*16+pg];
            float4 x1 = pr4[(c+1)*16+pg];
            float4 x2 = pr4[(c+2)*16+pg];
            float4 x3 = pr4[(c+3)*16+pg];
            #pragma unroll
            for (int j=0;j<4;++j)
                fma4(acc[j], W4[(o0+j)*16 + (c>>2)], x0,x1,x2,x3);
        }
        const float4* lb4 = (const float4*)lb;
        #pragma unroll
        for (int j=0;j<4;++j){
            float bs = bpost[o0+j];
            float4 lv = lb4[(size_t)(b*64 + o0+j)*16384 + (p0>>2) + pg];
            ft4[(64+o0+j)*16 + pg] = make_float4(acc[j][0]+bs+lv.x, acc[j][1]+bs+lv.y,
                                                 acc[j][2]+bs+lv.z, acc[j][3]+bs+lv.w);
        }
    }

    // ---- attention out: ft rows 0..63
    {
        const int ch0 = og*4;
        #pragma unroll
        for (int j = 0; j < 4; ++j) {
            int ch = ch0 + j;
            int hh = ch >> 3, c = ch & 7;
            const float* Ar = A + (size_t)(b*8+hh)*64 + c*8;
            float4 acc = make_float4(0.f,0.f,0.f,0.f);
            #pragma unroll
            for (int d = 0; d < 8; ++d) {
                float av = Ar[d];
                float4 vv = vt4[(hh*8+d)*16 + pg];
                acc.x += av*vv.x; acc.y += av*vv.y; acc.z += av*vv.z; acc.w += av*vv.w;
            }
            ft4[ch*16 + pg] = acc;
        }
    }
    __syncthreads();

    // ---- final proj (128x128) -> out
    {
        const int o0 = og*8;
        float acc[8][4];
        #pragma unroll
        for (int j=0;j<8;++j){acc[j][0]=0.f;acc[j][1]=0.f;acc[j][2]=0.f;acc[j][3]=0.f;}
        const float4* W4 = (const float4*)Wout;
        for (int c = 0; c < 128; c += 4) {
            float4 x0 = ft4[(c+0)*16+pg];
            float4 x1 = ft4[(c+1)*16+pg];
            float4 x2 = ft4[(c+2)*16+pg];
            float4 x3 = ft4[(c+3)*16+pg];
            #pragma unroll
            for (int j=0;j<8;++j)
                fma4(acc[j], W4[(o0+j)*32 + (c>>2)], x0,x1,x2,x3);
        }
        float4* out4 = (float4*)out;
        #pragma unroll
        for (int j=0;j<8;++j)
            out4[(size_t)(b*128 + o0+j)*16384 + (p0>>2) + pg] =
                make_float4(acc[j][0],acc[j][1],acc[j][2],acc[j][3]);
    }
}

// ---------------------------------------------------------------------------
extern "C" void kernel_launch(void* const* d_in, const int* in_sizes, int n_in,
                              void* d_out, int out_size, void* d_ws, size_t ws_size,
                              hipStream_t stream)
{
    const float* x     = (const float*)d_in[0];
    const float* Wp    = (const float*)d_in[1];
    const float* Wpre  = (const float*)d_in[2];
    const float* bpre  = (const float*)d_in[3];
    const float* w1    = (const float*)d_in[4];
    const float* b1    = (const float*)d_in[5];
    const float* w2    = (const float*)d_in[6];
    const float* b2    = (const float*)d_in[7];
    const float* sw    = (const float*)d_in[8];
    const float* sb    = (const float*)d_in[9];
    const float* Wpost = (const float*)d_in[10];
    const float* bpost = (const float*)d_in[11];
    const float* Wqkv  = (const float*)d_in[12];
    const float* dww   = (const float*)d_in[13];
    const float* Wg1   = (const float*)d_in[14];
    const float* bg1   = (const float*)d_in[15];
    const float* wg2   = (const float*)d_in[16];
    const float* bg2   = (const float*)d_in[17];
    const float* temp  = (const float*)d_in[18];
    const float* scales= (const float*)d_in[19];
    const float* Wout  = (const float*)d_in[20];
    float* out = (float*)d_out;

    float* ws = (float*)d_ws;
    float* pooled_part = ws;                 // 16384
    float* gate_part   = ws + 16384;         // 64
    float* thr_sum     = ws + 16448;         // 32
    float* sumsq       = ws + 16480;         // 512
    float* Sg          = ws + 16992;         // 2048
    float* cw          = ws + 19040;         // 256
    float* kdyn        = ws + 19296;         // 1
    float* thr         = ws + 19328;         // 32
    float* A           = ws + 19360;         // 2048

    float* lb  = ws + 32768;                 // 16,777,216 floats
    float* pre = lb  + 16777216;             // 16,777,216
    float* qkv = pre + 16777216;             // 50,331,648
    float* v   = qkv + 50331648;             // 16,777,216

    // zero the accumulators (pooled_part..Sg)
    hipMemsetAsync(ws, 0, (size_t)19040*sizeof(float), stream);

    k1_proj <<<4096, 256, 0, stream>>>(x, Wp, Wpre, bpre, Wqkv, Wg1, bg1, wg2, bg2,
                                       lb, pre, qkv, pooled_part, gate_part);
    k2_small<<<1,    256, 0, stream>>>(pooled_part, gate_part, w1, b1, w2, b2, cw, kdyn);
    k3_thr  <<<1024, 256, 0, stream>>>(pre, cw, sw, sb, thr_sum);
    k4_dw   <<<2048, 256, 0, stream>>>(qkv, dww, v, Sg, sumsq);
    k6_attn <<<1,    256, 0, stream>>>(Sg, sumsq, temp, kdyn, thr_sum, scales, A, thr);
    k7_final<<<4096, 256, 0, stream>>>(pre, lb, v, cw, thr, sw, sb, A,
                                       Wpost, bpost, Wout, out);
}

// Round 2
// 1293.454 us; speedup vs baseline: 1.5613x; 1.5613x over previous
//
#include <hip/hip_runtime.h>
#include <math.h>

#define HWN 65536

__device__ __forceinline__ float sgm(float x){ return 1.0f/(1.0f+expf(-x)); }

__device__ __forceinline__ void fma4(float acc[4], const float4 w,
                                     const float4 x0, const float4 x1,
                                     const float4 x2, const float4 x3){
    acc[0] += w.x*x0.x + w.y*x1.x + w.z*x2.x + w.w*x3.x;
    acc[1] += w.x*x0.y + w.y*x1.y + w.z*x2.y + w.w*x3.y;
    acc[2] += w.x*x0.z + w.y*x1.z + w.z*x2.z + w.w*x3.z;
    acc[3] += w.x*x0.w + w.y*x1.w + w.z*x2.w + w.w*x3.w;
}

// ---------------------------------------------------------------------------
// K1: input_proj + lb store + lgce_pre (+pooled partials) + qkv + gate scalar
// ---------------------------------------------------------------------------
__global__ __launch_bounds__(256,2) void k1_proj(
    const float* __restrict__ x,   const float* __restrict__ Wp,
    const float* __restrict__ Wpre,const float* __restrict__ bpre,
    const float* __restrict__ Wqkv,
    const float* __restrict__ Wg1, const float* __restrict__ bg1,
    const float* __restrict__ wg2, const float* __restrict__ bg2,
    float* __restrict__ lb, float* __restrict__ pre, float* __restrict__ qkv,
    float* __restrict__ pooled_part, float* __restrict__ gate_part)
{
    __shared__ float xt[128*64];
    __shared__ float pt[128*64];
    float* ht = xt;                       // reused after proj phase
    float4* xt4 = (float4*)xt;
    float4* pt4 = (float4*)pt;

    const int t    = threadIdx.x;
    const int blk  = blockIdx.x;
    const int b    = blk >> 10;           // 1024 blocks per batch
    const int p0   = (blk & 1023) << 6;   // 64 px / block
    const int pg   = t & 15;              // pixel group (4 px)
    const int og   = t >> 4;              // output group
    const int slot = blk & 63;

    const float4* x4 = (const float4*)x;
    #pragma unroll
    for (int i = 0; i < 8; ++i) {
        int idx = t + 256*i;
        int c = idx >> 4, q = idx & 15;
        xt4[c*16 + q] = x4[(size_t)(b*128 + c)*16384 + (p0>>2) + q];
    }
    __syncthreads();

    // ---- proj
    {
        const int o0 = og*8;
        float acc[8][4];
        #pragma unroll
        for (int j=0;j<8;++j){acc[j][0]=0.f;acc[j][1]=0.f;acc[j][2]=0.f;acc[j][3]=0.f;}
        const float4* W4 = (const float4*)Wp;
        for (int c = 0; c < 128; c += 4) {
            float4 x0 = xt4[(c+0)*16+pg];
            float4 x1 = xt4[(c+1)*16+pg];
            float4 x2 = xt4[(c+2)*16+pg];
            float4 x3 = xt4[(c+3)*16+pg];
            #pragma unroll
            for (int j=0;j<8;++j)
                fma4(acc[j], W4[(o0+j)*32 + (c>>2)], x0,x1,x2,x3);
        }
        #pragma unroll
        for (int j=0;j<8;++j)
            pt4[(o0+j)*16+pg] = make_float4(acc[j][0],acc[j][1],acc[j][2],acc[j][3]);
    }
    __syncthreads();

    // ---- lb to global
    {
        float4* lb4 = (float4*)lb;
        #pragma unroll
        for (int i=0;i<4;++i){
            int idx = t + 256*i;
            int c = idx >> 4, q = idx & 15;
            lb4[(size_t)(b*64 + c)*16384 + (p0>>2) + q] = pt4[c*16+q];
        }
    }

    // ---- pre conv (64x64) + pooled partial sums
    {
        const int o0 = og*4;
        float acc[4][4];
        #pragma unroll
        for (int j=0;j<4;++j){acc[j][0]=0.f;acc[j][1]=0.f;acc[j][2]=0.f;acc[j][3]=0.f;}
        const float4* W4 = (const float4*)Wpre;
        for (int c = 0; c < 64; c += 4) {
            float4 x0 = pt4[(c+0)*16+pg];
            float4 x1 = pt4[(c+1)*16+pg];
            float4 x2 = pt4[(c+2)*16+pg];
            float4 x3 = pt4[(c+3)*16+pg];
            #pragma unroll
            for (int j=0;j<4;++j)
                fma4(acc[j], W4[(o0+j)*16 + (c>>2)], x0,x1,x2,x3);
        }
        float4* pre4 = (float4*)pre;
        #pragma unroll
        for (int j=0;j<4;++j){
            float bs = bpre[o0+j];
            float4 vv = make_float4(acc[j][0]+bs, acc[j][1]+bs, acc[j][2]+bs, acc[j][3]+bs);
            pre4[(size_t)(b*64 + o0+j)*16384 + (p0>>2) + pg] = vv;
            float s = vv.x+vv.y+vv.z+vv.w;
            s += __shfl_xor(s,1); s += __shfl_xor(s,2);
            s += __shfl_xor(s,4); s += __shfl_xor(s,8);
            if (pg == 0) atomicAdd(&pooled_part[slot*256 + b*64 + o0 + j], s);
        }
    }

    // ---- qkv conv (192x64)
    {
        const int o0 = og*12;
        float acc[12][4];
        #pragma unroll
        for (int j=0;j<12;++j){acc[j][0]=0.f;acc[j][1]=0.f;acc[j][2]=0.f;acc[j][3]=0.f;}
        const float4* W4 = (const float4*)Wqkv;
        for (int c = 0; c < 64; c += 4) {
            float4 x0 = pt4[(64+c+0)*16+pg];
            float4 x1 = pt4[(64+c+1)*16+pg];
            float4 x2 = pt4[(64+c+2)*16+pg];
            float4 x3 = pt4[(64+c+3)*16+pg];
            #pragma unroll
            for (int j=0;j<12;++j)
                fma4(acc[j], W4[(o0+j)*16 + (c>>2)], x0,x1,x2,x3);
        }
        float4* qkv4 = (float4*)qkv;
        #pragma unroll
        for (int j=0;j<12;++j)
            qkv4[(size_t)(b*192 + o0+j)*16384 + (p0>>2) + pg] =
                make_float4(acc[j][0],acc[j][1],acc[j][2],acc[j][3]);
    }

    // ---- gate hidden (32x64) -> ht
    {
        const int o0 = og*2;
        float acc[2][4];
        #pragma unroll
        for (int j=0;j<2;++j){acc[j][0]=0.f;acc[j][1]=0.f;acc[j][2]=0.f;acc[j][3]=0.f;}
        const float4* W4 = (const float4*)Wg1;
        for (int c = 0; c < 64; c += 4) {
            float4 x0 = pt4[(64+c+0)*16+pg];
            float4 x1 = pt4[(64+c+1)*16+pg];
            float4 x2 = pt4[(64+c+2)*16+pg];
            float4 x3 = pt4[(64+c+3)*16+pg];
            #pragma unroll
            for (int j=0;j<2;++j)
                fma4(acc[j], W4[(o0+j)*16 + (c>>2)], x0,x1,x2,x3);
        }
        #pragma unroll
        for (int j=0;j<2;++j){
            float bs = bg1[o0+j];
            #pragma unroll
            for (int k=0;k<4;++k)
                ht[(o0+j)*64 + pg*4 + k] = fmaxf(acc[j][k]+bs, 0.0f);
        }
    }
    __syncthreads();

    if (t < 64) {
        float g = bg2[0];
        #pragma unroll
        for (int c = 0; c < 32; ++c) g += wg2[c]*ht[c*64 + t];
        g = sgm(g);
        g += __shfl_xor(g,1);  g += __shfl_xor(g,2);  g += __shfl_xor(g,4);
        g += __shfl_xor(g,8);  g += __shfl_xor(g,16); g += __shfl_xor(g,32);
        if (t == 0) atomicAdd(&gate_part[slot], g);
    }
}

// ---------------------------------------------------------------------------
// K2: pooled -> cw, gate mean -> kdyn. single block.
// ---------------------------------------------------------------------------
__global__ void k2_small(const float* __restrict__ pooled_part,
                         const float* __restrict__ gate_part,
                         const float* __restrict__ w1, const float* __restrict__ b1,
                         const float* __restrict__ w2, const float* __restrict__ b2,
                         float* __restrict__ cw, float* __restrict__ kdyn)
{
    __shared__ float pl[256];
    const int t = threadIdx.x;
    float s = 0.f;
    for (int sl = 0; sl < 64; ++sl) s += pooled_part[sl*256 + t];
    pl[t] = s * (1.0f/65536.0f);
    __syncthreads();
    const int b = t >> 6, g = (t >> 3) & 7, c = t & 7;
    float h0 = b1[g*2+0], h1 = b1[g*2+1];
    #pragma unroll
    for (int cc = 0; cc < 8; ++cc) {
        float p = pl[b*64 + g*8 + cc];
        h0 += p*w1[g*16 + 0*8 + cc];
        h1 += p*w1[g*16 + 1*8 + cc];
    }
    h0 = fmaxf(h0, 0.f); h1 = fmaxf(h1, 0.f);
    cw[t] = sgm(h0*w2[g*16 + c*2 + 0] + h1*w2[g*16 + c*2 + 1] + b2[g*8+c]);
    if (t == 0) {
        float gs = 0.f;
        for (int sl = 0; sl < 64; ++sl) gs += gate_part[sl];
        float kd = floorf(8.0f * (gs * (1.0f/262144.0f)));
        *kdyn = fminf(fmaxf(kd, 1.0f), 8.0f);
    }
}

// ---------------------------------------------------------------------------
// K3: resp partial sums for thr.
// ---------------------------------------------------------------------------
__global__ __launch_bounds__(256) void k3_thr(
    const float* __restrict__ pre, const float* __restrict__ cw,
    const float* __restrict__ sw,  const float* __restrict__ sb,
    float* __restrict__ thr_sum)
{
    __shared__ float part[4][8];
    const int t = threadIdx.x;
    const int b = blockIdx.x >> 8;
    const int p = ((blockIdx.x & 255) << 8) + t;
    float rs[8];
    #pragma unroll
    for (int g = 0; g < 8; ++g) {
        float xc[8];
        float spa = sb[g];
        #pragma unroll
        for (int c = 0; c < 8; ++c) {
            float xv = pre[(size_t)(b*64 + g*8 + c)*HWN + p];
            xc[c] = xv * cw[b*64 + g*8 + c];
            spa += xc[c]*sw[g*8 + c];
        }
        float sp = sgm(spa);
        float s = 0.f;
        #pragma unroll
        for (int c = 0; c < 8; ++c) s += sgm(xc[c]*sp);
        rs[g] = s;
    }
    const int lane = t & 63, wv = t >> 6;
    #pragma unroll
    for (int g = 0; g < 8; ++g) {
        float val = rs[g];
        val += __shfl_xor(val,1);  val += __shfl_xor(val,2);  val += __shfl_xor(val,4);
        val += __shfl_xor(val,8);  val += __shfl_xor(val,16); val += __shfl_xor(val,32);
        if (lane == 0) part[wv][g] = val;
    }
    __syncthreads();
    if (t < 8)
        atomicAdd(&thr_sum[b*8 + t], part[0][t]+part[1][t]+part[2][t]+part[3][t]);
}

// ---------------------------------------------------------------------------
// K4 (REWRITTEN): depthwise 3x3; block = (b, h, 8-row band of 256 cols).
// Double-buffered LDS, one barrier/channel, coalesced float4 staging,
// next-channel loads issued before the barrier (latency overlap).
// Writes v; accumulates q.k gram + q/k sumsq via shuffle+atomics.
// ---------------------------------------------------------------------------
#define K4_ROWSTRIDE 264            // 4 pad | 256 data | 4 pad (floats)
#define K4_BUF (10*K4_ROWSTRIDE)    // 10 halo rows

__global__ __launch_bounds__(256,3) void k4_dw(
    const float* __restrict__ qkv, const float* __restrict__ dww,
    float* __restrict__ v, float* __restrict__ Sg, float* __restrict__ sumsq)
{
    __shared__ float sh[2*K4_BUF];  // 21120 B

    const int t    = threadIdx.x;
    const int b    = blockIdx.x >> 8;         // 256 blocks / batch
    const int h    = (blockIdx.x >> 5) & 7;
    const int band = blockIdx.x & 31;
    const int r0   = band * 8;
    const int lr   = t >> 5;                  // output row 0..7
    const int c0   = (t & 31) * 4;            // group0 cols c0..c0+3; group1 +128

    // edge columns (global col -1 and 256) are always zero; init once per buffer
    if (t < 40) {
        int bufi = t / 20, r = (t % 20) >> 1, side = t & 1;
        sh[bufi*K4_BUF + r*K4_ROWSTRIDE + (side ? 260 : 3)] = 0.0f;
    }

    float4 reg[3];

    // stage global loads for channel ch (absolute channel in [0,192)) into regs
    auto issue_loads = [&](int ch) {
        const float4* base = (const float4*)(qkv + (size_t)(b*192 + ch)*HWN);
        #pragma unroll
        for (int j = 0; j < 3; ++j) {
            int i = t + 256*j;
            float4 val = make_float4(0.f,0.f,0.f,0.f);
            if (i < 640) {
                int row = i >> 6, col4 = i & 63;
                int gy = r0 - 1 + row;
                if (gy >= 0 && gy < 256) val = base[gy*64 + col4];
            }
            reg[j] = val;
        }
    };

    auto write_lds = [&](float* buf) {
        #pragma unroll
        for (int j = 0; j < 3; ++j) {
            int i = t + 256*j;
            if (i < 640) {
                int row = i >> 6, col4 = i & 63;
                *(float4*)&buf[row*K4_ROWSTRIDE + 4 + col4*4] = reg[j];
            }
        }
    };

    // conv 3x3 on LDS buffer -> 8 px (2 groups of 4)
    auto conv8 = [&](const float* buf, const float* __restrict__ w9, float out[8]) {
        #pragma unroll
        for (int g = 0; g < 2; ++g) {
            const int cc = c0 + g*128;
            float a0=0.f, a1=0.f, a2=0.f, a3=0.f;
            #pragma unroll
            for (int rr = 0; rr < 3; ++rr) {
                const float* row = &buf[(lr+rr)*K4_ROWSTRIDE + 4 + cc];
                float4 m = *(const float4*)row;
                float l = row[-1], r = row[4];
                float w0 = w9[rr*3+0], w1 = w9[rr*3+1], w2 = w9[rr*3+2];
                a0 = fmaf(w0,l,   fmaf(w1,m.x, fmaf(w2,m.y, a0)));
                a1 = fmaf(w0,m.x, fmaf(w1,m.y, fmaf(w2,m.z, a1)));
                a2 = fmaf(w0,m.y, fmaf(w1,m.z, fmaf(w2,m.w, a2)));
                a3 = fmaf(w0,m.z, fmaf(w1,m.w, fmaf(w2,r,   a3)));
            }
            out[g*4+0]=a0; out[g*4+1]=a1; out[g*4+2]=a2; out[g*4+3]=a3;
        }
    };

    float dq[8][8];
    float S[64];
    #pragma unroll
    for (int i = 0; i < 64; ++i) S[i] = 0.f;
    float sk[8];

    issue_loads(h*8 + 0);   // first q channel

    // ---- Q channels (parity = ch&1)
    #pragma unroll
    for (int ch = 0; ch < 8; ++ch) {
        float* buf = sh + (ch & 1)*K4_BUF;
        write_lds(buf);
        issue_loads(ch < 7 ? (h*8 + ch + 1) : (64 + h*8));
        __syncthreads();
        conv8(buf, dww + (h*8 + ch)*9, dq[ch]);
    }

    // ---- K channels
    #pragma unroll
    for (int ch = 0; ch < 8; ++ch) {
        float* buf = sh + (ch & 1)*K4_BUF;
        write_lds(buf);
        issue_loads(ch < 7 ? (64 + h*8 + ch + 1) : (128 + h*8));
        __syncthreads();
        float dk[8];
        conv8(buf, dww + (64 + h*8 + ch)*9, dk);
        float s2 = 0.f;
        #pragma unroll
        for (int p = 0; p < 8; ++p) s2 += dk[p]*dk[p];
        sk[ch] = s2;
        #pragma unroll
        for (int c = 0; c < 8; ++c) {
            float acc = S[c*8 + ch];
            #pragma unroll
            for (int p = 0; p < 8; ++p) acc = fmaf(dq[c][p], dk[p], acc);
            S[c*8 + ch] = acc;
        }
    }

    // ---- V channels (compute + store only)
    #pragma unroll
    for (int ch = 0; ch < 8; ++ch) {
        float* buf = sh + (ch & 1)*K4_BUF;
        write_lds(buf);
        if (ch < 7) issue_loads(128 + h*8 + ch + 1);
        __syncthreads();
        float dv[8];
        conv8(buf, dww + (128 + h*8 + ch)*9, dv);
        float* vb = v + (size_t)(b*64 + h*8 + ch)*HWN + (r0 + lr)*256;
        *(float4*)&vb[c0]       = make_float4(dv[0],dv[1],dv[2],dv[3]);
        *(float4*)&vb[c0 + 128] = make_float4(dv[4],dv[5],dv[6],dv[7]);
    }

    // ---- reductions
    const int lane = t & 63;
    #pragma unroll
    for (int i = 0; i < 64; ++i) {
        float val = S[i];
        val += __shfl_xor(val,1);  val += __shfl_xor(val,2);  val += __shfl_xor(val,4);
        val += __shfl_xor(val,8);  val += __shfl_xor(val,16); val += __shfl_xor(val,32);
        if (lane == 0) atomicAdd(&Sg[(b*8+h)*64 + i], val);
    }
    #pragma unroll
    for (int c = 0; c < 8; ++c) {
        float v1 = 0.f;
        #pragma unroll
        for (int p = 0; p < 8; ++p) v1 += dq[c][p]*dq[c][p];
        float v2 = sk[c];
        v1 += __shfl_xor(v1,1);  v1 += __shfl_xor(v1,2);  v1 += __shfl_xor(v1,4);
        v1 += __shfl_xor(v1,8);  v1 += __shfl_xor(v1,16); v1 += __shfl_xor(v1,32);
        v2 += __shfl_xor(v2,1);  v2 += __shfl_xor(v2,2);  v2 += __shfl_xor(v2,4);
        v2 += __shfl_xor(v2,8);  v2 += __shfl_xor(v2,16); v2 += __shfl_xor(v2,32);
        if (lane == 0) {
            atomicAdd(&sumsq[b*128 + h*8 + c], v1);
            atomicAdd(&sumsq[b*128 + 64 + h*8 + c], v2);
        }
    }
}

// ---------------------------------------------------------------------------
// K6: finalize attention weights and thr. single block.
// ---------------------------------------------------------------------------
__global__ void k6_attn(const float* __restrict__ Sg, const float* __restrict__ sumsq,
                        const float* __restrict__ temp, const float* __restrict__ kdynp,
                        const float* __restrict__ thr_sum, const float* __restrict__ scales,
                        float* __restrict__ A, float* __restrict__ thr)
{
    const int t = threadIdx.x;
    if (t < 32) thr[t] = thr_sum[t] * (1.0f/(8.0f*65536.0f));
    const int b = t >> 6, h = (t >> 3) & 7, c = t & 7;
    const float kd = *kdynp;
    const float ssum = scales[0]+scales[1]+scales[2]+scales[3];
    const float nq = fmaxf(sqrtf(sumsq[b*128 + h*8 + c]), 1e-12f);
    const float tv = temp[h];
    const float* Srow = Sg + (size_t)(b*8+h)*64 + c*8;
    float a[8];
    #pragma unroll
    for (int d = 0; d < 8; ++d) {
        float nk = fmaxf(sqrtf(sumsq[b*128 + 64 + h*8 + d]), 1e-12f);
        a[d] = Srow[d] / (nq*nk) * tv;
    }
    bool keep[8];
    #pragma unroll
    for (int d = 0; d < 8; ++d) {
        int r = 0;
        #pragma unroll
        for (int e = 0; e < 8; ++e)
            r += (a[e] > a[d]) || (a[e] == a[d] && e < d);
        keep[d] = ((float)r < kd);
    }
    float m = -INFINITY;
    #pragma unroll
    for (int d = 0; d < 8; ++d) if (keep[d]) m = fmaxf(m, a[d]);
    float ex[8]; float sum = 0.f;
    #pragma unroll
    for (int d = 0; d < 8; ++d) { ex[d] = keep[d] ? expf(a[d]-m) : 0.f; sum += ex[d]; }
    const float inv = ssum / sum;
    #pragma unroll
    for (int d = 0; d < 8; ++d)
        A[(size_t)(b*8+h)*64 + c*8 + d] = ex[d]*inv;
}

// ---------------------------------------------------------------------------
// K7: mask path + post conv + residual + attn@v + proj_out, fused epilogue.
// ---------------------------------------------------------------------------
__global__ __launch_bounds__(256,2) void k7_final(
    const float* __restrict__ pre, const float* __restrict__ lb, const float* __restrict__ v,
    const float* __restrict__ cw,  const float* __restrict__ thr,
    const float* __restrict__ sw,  const float* __restrict__ sb,
    const float* __restrict__ A,
    const float* __restrict__ Wpost, const float* __restrict__ bpost,
    const float* __restrict__ Wout,  float* __restrict__ out)
{
    __shared__ float pr[64*64];
    __shared__ float vt[64*64];
    __shared__ float ft[128*64];
    float4* pr4 = (float4*)pr;
    float4* vt4 = (float4*)vt;
    float4* ft4 = (float4*)ft;

    const int t   = threadIdx.x;
    const int blk = blockIdx.x;
    const int b   = blk >> 10;
    const int p0  = (blk & 1023) << 6;
    const int pg  = t & 15;
    const int og  = t >> 4;

    const float4* pre4g = (const float4*)pre;
    const float4* v4g   = (const float4*)v;
    #pragma unroll
    for (int i = 0; i < 4; ++i) {
        int idx = t + 256*i;
        int c = idx >> 4, q = idx & 15;
        size_t gi = (size_t)(b*64 + c)*16384 + (p0>>2) + q;
        pr4[c*16+q] = pre4g[gi];
        vt4[c*16+q] = v4g[gi];
    }
    __syncthreads();

    #pragma unroll
    for (int s = 0; s < 2; ++s) {
        int task = t + 256*s;
        int g = task >> 6, px = task & 63;
        float xc[8], xv[8];
        float spa = sb[g];
        #pragma unroll
        for (int c = 0; c < 8; ++c) {
            xv[c] = pr[(g*8+c)*64 + px];
            xc[c] = xv[c]*cw[b*64 + g*8 + c];
            spa += xc[c]*sw[g*8 + c];
        }
        float sp = sgm(spa);
        float th = thr[b*8 + g];
        #pragma unroll
        for (int c = 0; c < 8; ++c) {
            float resp = sgm(xc[c]*sp);
            float mask = resp > th ? 1.0f : resp;
            pr[(g*8+c)*64 + px] = xv[c]*mask;
        }
    }
    __syncthreads();

    {
        const int o0 = og*4;
        float acc[4][4];
        #pragma unroll
        for (int j=0;j<4;++j){acc[j][0]=0.f;acc[j][1]=0.f;acc[j][2]=0.f;acc[j][3]=0.f;}
        const float4* W4 = (const float4*)Wpost;
        for (int c = 0; c < 64; c += 4) {
            float4 x0 = pr4[(c+0)*16+pg];
            float4 x1 = pr4[(c+1)*16+pg];
            float4 x2 = pr4[(c+2)*16+pg];
            float4 x3 = pr4[(c+3)*16+pg];
            #pragma unroll
            for (int j=0;j<4;++j)
                fma4(acc[j], W4[(o0+j)*16 + (c>>2)], x0,x1,x2,x3);
        }
        const float4* lb4 = (const float4*)lb;
        #pragma unroll
        for (int j=0;j<4;++j){
            float bs = bpost[o0+j];
            float4 lv = lb4[(size_t)(b*64 + o0+j)*16384 + (p0>>2) + pg];
            ft4[(64+o0+j)*16 + pg] = make_float4(acc[j][0]+bs+lv.x, acc[j][1]+bs+lv.y,
                                                 acc[j][2]+bs+lv.z, acc[j][3]+bs+lv.w);
        }
    }

    {
        const int ch0 = og*4;
        #pragma unroll
        for (int j = 0; j < 4; ++j) {
            int ch = ch0 + j;
            int hh = ch >> 3, c = ch & 7;
            const float* Ar = A + (size_t)(b*8+hh)*64 + c*8;
            float4 acc = make_float4(0.f,0.f,0.f,0.f);
            #pragma unroll
            for (int d = 0; d < 8; ++d) {
                float av = Ar[d];
                float4 vv = vt4[(hh*8+d)*16 + pg];
                acc.x += av*vv.x; acc.y += av*vv.y; acc.z += av*vv.z; acc.w += av*vv.w;
            }
            ft4[ch*16 + pg] = acc;
        }
    }
    __syncthreads();

    {
        const int o0 = og*8;
        float acc[8][4];
        #pragma unroll
        for (int j=0;j<8;++j){acc[j][0]=0.f;acc[j][1]=0.f;acc[j][2]=0.f;acc[j][3]=0.f;}
        const float4* W4 = (const float4*)Wout;
        for (int c = 0; c < 128; c += 4) {
            float4 x0 = ft4[(c+0)*16+pg];
            float4 x1 = ft4[(c+1)*16+pg];
            float4 x2 = ft4[(c+2)*16+pg];
            float4 x3 = ft4[(c+3)*16+pg];
            #pragma unroll
            for (int j=0;j<8;++j)
                fma4(acc[j], W4[(o0+j)*32 + (c>>2)], x0,x1,x2,x3);
        }
        float4* out4 = (float4*)out;
        #pragma unroll
        for (int j=0;j<8;++j)
            out4[(size_t)(b*128 + o0+j)*16384 + (p0>>2) + pg] =
                make_float4(acc[j][0],acc[j][1],acc[j][2],acc[j][3]);
    }
}

// ---------------------------------------------------------------------------
extern "C" void kernel_launch(void* const* d_in, const int* in_sizes, int n_in,
                              void* d_out, int out_size, void* d_ws, size_t ws_size,
                              hipStream_t stream)
{
    const float* x     = (const float*)d_in[0];
    const float* Wp    = (const float*)d_in[1];
    const float* Wpre  = (const float*)d_in[2];
    const float* bpre  = (const float*)d_in[3];
    const float* w1    = (const float*)d_in[4];
    const float* b1    = (const float*)d_in[5];
    const float* w2    = (const float*)d_in[6];
    const float* b2    = (const float*)d_in[7];
    const float* sw    = (const float*)d_in[8];
    const float* sb    = (const float*)d_in[9];
    const float* Wpost = (const float*)d_in[10];
    const float* bpost = (const float*)d_in[11];
    const float* Wqkv  = (const float*)d_in[12];
    const float* dww   = (const float*)d_in[13];
    const float* Wg1   = (const float*)d_in[14];
    const float* bg1   = (const float*)d_in[15];
    const float* wg2   = (const float*)d_in[16];
    const float* bg2   = (const float*)d_in[17];
    const float* temp  = (const float*)d_in[18];
    const float* scales= (const float*)d_in[19];
    const float* Wout  = (const float*)d_in[20];
    float* out = (float*)d_out;

    float* ws = (float*)d_ws;
    float* pooled_part = ws;                 // 16384
    float* gate_part   = ws + 16384;         // 64
    float* thr_sum     = ws + 16448;         // 32
    float* sumsq       = ws + 16480;         // 512
    float* Sg          = ws + 16992;         // 2048
    float* cw          = ws + 19040;         // 256
    float* kdyn        = ws + 19296;         // 1
    float* thr         = ws + 19328;         // 32
    float* A           = ws + 19360;         // 2048

    float* lb  = ws + 32768;
    float* pre = lb  + 16777216;
    float* qkv = pre + 16777216;
    float* v   = qkv + 50331648;

    hipMemsetAsync(ws, 0, (size_t)19040*sizeof(float), stream);

    k1_proj <<<4096, 256, 0, stream>>>(x, Wp, Wpre, bpre, Wqkv, Wg1, bg1, wg2, bg2,
                                       lb, pre, qkv, pooled_part, gate_part);
    k2_small<<<1,    256, 0, stream>>>(pooled_part, gate_part, w1, b1, w2, b2, cw, kdyn);
    k3_thr  <<<1024, 256, 0, stream>>>(pre, cw, sw, sb, thr_sum);
    k4_dw   <<<1024, 256, 0, stream>>>(qkv, dww, v, Sg, sumsq);
    k6_attn <<<1,    256, 0, stream>>>(Sg, sumsq, temp, kdyn, thr_sum, scales, A, thr);
    k7_final<<<4096, 256, 0, stream>>>(pre, lb, v, cw, thr, sw, sb, A,
                                       Wpost, bpost, Wout, out);
}

// Round 3
// 1249.796 us; speedup vs baseline: 1.6158x; 1.0349x over previous
//
#include <hip/hip_runtime.h>
#include <math.h>

#define HWN 65536

__device__ __forceinline__ float sgm(float x){ return 1.0f/(1.0f+expf(-x)); }

__device__ __forceinline__ void fma4(float acc[4], const float4 w,
                                     const float4 x0, const float4 x1,
                                     const float4 x2, const float4 x3){
    acc[0] += w.x*x0.x + w.y*x1.x + w.z*x2.x + w.w*x3.x;
    acc[1] += w.x*x0.y + w.y*x1.y + w.z*x2.y + w.w*x3.y;
    acc[2] += w.x*x0.z + w.y*x1.z + w.z*x2.z + w.w*x3.z;
    acc[3] += w.x*x0.w + w.y*x1.w + w.z*x2.w + w.w*x3.w;
}

// ---------------------------------------------------------------------------
// K1: input_proj + lb store + lgce_pre (+pooled partials) + qkv + gate scalar
// ---------------------------------------------------------------------------
__global__ __launch_bounds__(256,2) void k1_proj(
    const float* __restrict__ x,   const float* __restrict__ Wp,
    const float* __restrict__ Wpre,const float* __restrict__ bpre,
    const float* __restrict__ Wqkv,
    const float* __restrict__ Wg1, const float* __restrict__ bg1,
    const float* __restrict__ wg2, const float* __restrict__ bg2,
    float* __restrict__ lb, float* __restrict__ pre, float* __restrict__ qkv,
    float* __restrict__ pooled_part, float* __restrict__ gate_part)
{
    __shared__ float xt[128*64];
    __shared__ float pt[128*64];
    float* ht = xt;                       // reused after proj phase
    float4* xt4 = (float4*)xt;
    float4* pt4 = (float4*)pt;

    const int t    = threadIdx.x;
    const int blk  = blockIdx.x;
    const int b    = blk >> 10;           // 1024 blocks per batch
    const int p0   = (blk & 1023) << 6;   // 64 px / block
    const int pg   = t & 15;              // pixel group (4 px)
    const int og   = t >> 4;              // output group
    const int slot = blk & 63;

    const float4* x4 = (const float4*)x;
    #pragma unroll
    for (int i = 0; i < 8; ++i) {
        int idx = t + 256*i;
        int c = idx >> 4, q = idx & 15;
        xt4[c*16 + q] = x4[(size_t)(b*128 + c)*16384 + (p0>>2) + q];
    }
    __syncthreads();

    // ---- proj
    {
        const int o0 = og*8;
        float acc[8][4];
        #pragma unroll
        for (int j=0;j<8;++j){acc[j][0]=0.f;acc[j][1]=0.f;acc[j][2]=0.f;acc[j][3]=0.f;}
        const float4* W4 = (const float4*)Wp;
        for (int c = 0; c < 128; c += 4) {
            float4 x0 = xt4[(c+0)*16+pg];
            float4 x1 = xt4[(c+1)*16+pg];
            float4 x2 = xt4[(c+2)*16+pg];
            float4 x3 = xt4[(c+3)*16+pg];
            #pragma unroll
            for (int j=0;j<8;++j)
                fma4(acc[j], W4[(o0+j)*32 + (c>>2)], x0,x1,x2,x3);
        }
        #pragma unroll
        for (int j=0;j<8;++j)
            pt4[(o0+j)*16+pg] = make_float4(acc[j][0],acc[j][1],acc[j][2],acc[j][3]);
    }
    __syncthreads();

    // ---- lb to global
    {
        float4* lb4 = (float4*)lb;
        #pragma unroll
        for (int i=0;i<4;++i){
            int idx = t + 256*i;
            int c = idx >> 4, q = idx & 15;
            lb4[(size_t)(b*64 + c)*16384 + (p0>>2) + q] = pt4[c*16+q];
        }
    }

    // ---- pre conv (64x64) + pooled partial sums
    {
        const int o0 = og*4;
        float acc[4][4];
        #pragma unroll
        for (int j=0;j<4;++j){acc[j][0]=0.f;acc[j][1]=0.f;acc[j][2]=0.f;acc[j][3]=0.f;}
        const float4* W4 = (const float4*)Wpre;
        for (int c = 0; c < 64; c += 4) {
            float4 x0 = pt4[(c+0)*16+pg];
            float4 x1 = pt4[(c+1)*16+pg];
            float4 x2 = pt4[(c+2)*16+pg];
            float4 x3 = pt4[(c+3)*16+pg];
            #pragma unroll
            for (int j=0;j<4;++j)
                fma4(acc[j], W4[(o0+j)*16 + (c>>2)], x0,x1,x2,x3);
        }
        float4* pre4 = (float4*)pre;
        #pragma unroll
        for (int j=0;j<4;++j){
            float bs = bpre[o0+j];
            float4 vv = make_float4(acc[j][0]+bs, acc[j][1]+bs, acc[j][2]+bs, acc[j][3]+bs);
            pre4[(size_t)(b*64 + o0+j)*16384 + (p0>>2) + pg] = vv;
            float s = vv.x+vv.y+vv.z+vv.w;
            s += __shfl_xor(s,1); s += __shfl_xor(s,2);
            s += __shfl_xor(s,4); s += __shfl_xor(s,8);
            if (pg == 0) atomicAdd(&pooled_part[slot*256 + b*64 + o0 + j], s);
        }
    }

    // ---- qkv conv (192x64)
    {
        const int o0 = og*12;
        float acc[12][4];
        #pragma unroll
        for (int j=0;j<12;++j){acc[j][0]=0.f;acc[j][1]=0.f;acc[j][2]=0.f;acc[j][3]=0.f;}
        const float4* W4 = (const float4*)Wqkv;
        for (int c = 0; c < 64; c += 4) {
            float4 x0 = pt4[(64+c+0)*16+pg];
            float4 x1 = pt4[(64+c+1)*16+pg];
            float4 x2 = pt4[(64+c+2)*16+pg];
            float4 x3 = pt4[(64+c+3)*16+pg];
            #pragma unroll
            for (int j=0;j<12;++j)
                fma4(acc[j], W4[(o0+j)*16 + (c>>2)], x0,x1,x2,x3);
        }
        float4* qkv4 = (float4*)qkv;
        #pragma unroll
        for (int j=0;j<12;++j)
            qkv4[(size_t)(b*192 + o0+j)*16384 + (p0>>2) + pg] =
                make_float4(acc[j][0],acc[j][1],acc[j][2],acc[j][3]);
    }

    // ---- gate hidden (32x64) -> ht
    {
        const int o0 = og*2;
        float acc[2][4];
        #pragma unroll
        for (int j=0;j<2;++j){acc[j][0]=0.f;acc[j][1]=0.f;acc[j][2]=0.f;acc[j][3]=0.f;}
        const float4* W4 = (const float4*)Wg1;
        for (int c = 0; c < 64; c += 4) {
            float4 x0 = pt4[(64+c+0)*16+pg];
            float4 x1 = pt4[(64+c+1)*16+pg];
            float4 x2 = pt4[(64+c+2)*16+pg];
            float4 x3 = pt4[(64+c+3)*16+pg];
            #pragma unroll
            for (int j=0;j<2;++j)
                fma4(acc[j], W4[(o0+j)*16 + (c>>2)], x0,x1,x2,x3);
        }
        #pragma unroll
        for (int j=0;j<2;++j){
            float bs = bg1[o0+j];
            #pragma unroll
            for (int k=0;k<4;++k)
                ht[(o0+j)*64 + pg*4 + k] = fmaxf(acc[j][k]+bs, 0.0f);
        }
    }
    __syncthreads();

    if (t < 64) {
        float g = bg2[0];
        #pragma unroll
        for (int c = 0; c < 32; ++c) g += wg2[c]*ht[c*64 + t];
        g = sgm(g);
        g += __shfl_xor(g,1);  g += __shfl_xor(g,2);  g += __shfl_xor(g,4);
        g += __shfl_xor(g,8);  g += __shfl_xor(g,16); g += __shfl_xor(g,32);
        if (t == 0) atomicAdd(&gate_part[slot], g);
    }
}

// ---------------------------------------------------------------------------
// K2: pooled -> cw, gate mean -> kdyn. single block.
// ---------------------------------------------------------------------------
__global__ void k2_small(const float* __restrict__ pooled_part,
                         const float* __restrict__ gate_part,
                         const float* __restrict__ w1, const float* __restrict__ b1,
                         const float* __restrict__ w2, const float* __restrict__ b2,
                         float* __restrict__ cw, float* __restrict__ kdyn)
{
    __shared__ float pl[256];
    const int t = threadIdx.x;
    float s = 0.f;
    for (int sl = 0; sl < 64; ++sl) s += pooled_part[sl*256 + t];
    pl[t] = s * (1.0f/65536.0f);
    __syncthreads();
    const int b = t >> 6, g = (t >> 3) & 7, c = t & 7;
    float h0 = b1[g*2+0], h1 = b1[g*2+1];
    #pragma unroll
    for (int cc = 0; cc < 8; ++cc) {
        float p = pl[b*64 + g*8 + cc];
        h0 += p*w1[g*16 + 0*8 + cc];
        h1 += p*w1[g*16 + 1*8 + cc];
    }
    h0 = fmaxf(h0, 0.f); h1 = fmaxf(h1, 0.f);
    cw[t] = sgm(h0*w2[g*16 + c*2 + 0] + h1*w2[g*16 + c*2 + 1] + b2[g*8+c]);
    if (t == 0) {
        float gs = 0.f;
        for (int sl = 0; sl < 64; ++sl) gs += gate_part[sl];
        float kd = floorf(8.0f * (gs * (1.0f/262144.0f)));
        *kdyn = fminf(fmaxf(kd, 1.0f), 8.0f);
    }
}

// ---------------------------------------------------------------------------
// K3: resp partial sums for thr.
// ---------------------------------------------------------------------------
__global__ __launch_bounds__(256) void k3_thr(
    const float* __restrict__ pre, const float* __restrict__ cw,
    const float* __restrict__ sw,  const float* __restrict__ sb,
    float* __restrict__ thr_sum)
{
    __shared__ float part[4][8];
    const int t = threadIdx.x;
    const int b = blockIdx.x >> 8;
    const int p = ((blockIdx.x & 255) << 8) + t;
    float rs[8];
    #pragma unroll
    for (int g = 0; g < 8; ++g) {
        float xc[8];
        float spa = sb[g];
        #pragma unroll
        for (int c = 0; c < 8; ++c) {
            float xv = pre[(size_t)(b*64 + g*8 + c)*HWN + p];
            xc[c] = xv * cw[b*64 + g*8 + c];
            spa += xc[c]*sw[g*8 + c];
        }
        float sp = sgm(spa);
        float s = 0.f;
        #pragma unroll
        for (int c = 0; c < 8; ++c) s += sgm(xc[c]*sp);
        rs[g] = s;
    }
    const int lane = t & 63, wv = t >> 6;
    #pragma unroll
    for (int g = 0; g < 8; ++g) {
        float val = rs[g];
        val += __shfl_xor(val,1);  val += __shfl_xor(val,2);  val += __shfl_xor(val,4);
        val += __shfl_xor(val,8);  val += __shfl_xor(val,16); val += __shfl_xor(val,32);
        if (lane == 0) part[wv][g] = val;
    }
    __syncthreads();
    if (t < 8)
        atomicAdd(&thr_sum[b*8 + t], part[0][t]+part[1][t]+part[2][t]+part[3][t]);
}

// ---------------------------------------------------------------------------
// K4: depthwise 3x3; block = (b, h, 8-row band of 256 cols).
// Double-buffered LDS, one barrier/channel, coalesced float4 staging,
// next-channel loads issued before the barrier (latency overlap).
// launch_bounds(256,2): 256-VGPR budget so dq[8][8]+S[64] stay in registers
// (R2's (256,3) cap at ~170 VGPRs spilled ~0.5 GB/way of scratch traffic).
// ---------------------------------------------------------------------------
#define K4_ROWSTRIDE 264            // 4 pad | 256 data | 4 pad (floats)
#define K4_BUF (10*K4_ROWSTRIDE)    // 10 halo rows

__global__ __launch_bounds__(256,2) void k4_dw(
    const float* __restrict__ qkv, const float* __restrict__ dww,
    float* __restrict__ v, float* __restrict__ Sg, float* __restrict__ sumsq)
{
    __shared__ float sh[2*K4_BUF];  // 21120 B

    const int t    = threadIdx.x;
    const int b    = blockIdx.x >> 8;         // 256 blocks / batch
    const int h    = (blockIdx.x >> 5) & 7;
    const int band = blockIdx.x & 31;
    const int r0   = band * 8;
    const int lr   = t >> 5;                  // output row 0..7
    const int c0   = (t & 31) * 4;            // group0 cols c0..c0+3; group1 +128

    // edge columns (global col -1 and 256) are always zero; init once per buffer
    if (t < 40) {
        int bufi = t / 20, r = (t % 20) >> 1, side = t & 1;
        sh[bufi*K4_BUF + r*K4_ROWSTRIDE + (side ? 260 : 3)] = 0.0f;
    }

    float4 reg[3];

    auto issue_loads = [&](int ch) {
        const float4* base = (const float4*)(qkv + (size_t)(b*192 + ch)*HWN);
        #pragma unroll
        for (int j = 0; j < 3; ++j) {
            int i = t + 256*j;
            float4 val = make_float4(0.f,0.f,0.f,0.f);
            if (i < 640) {
                int row = i >> 6, col4 = i & 63;
                int gy = r0 - 1 + row;
                if (gy >= 0 && gy < 256) val = base[gy*64 + col4];
            }
            reg[j] = val;
        }
    };

    auto write_lds = [&](float* buf) {
        #pragma unroll
        for (int j = 0; j < 3; ++j) {
            int i = t + 256*j;
            if (i < 640) {
                int row = i >> 6, col4 = i & 63;
                *(float4*)&buf[row*K4_ROWSTRIDE + 4 + col4*4] = reg[j];
            }
        }
    };

    auto conv8 = [&](const float* buf, const float* __restrict__ w9, float out[8]) {
        #pragma unroll
        for (int g = 0; g < 2; ++g) {
            const int cc = c0 + g*128;
            float a0=0.f, a1=0.f, a2=0.f, a3=0.f;
            #pragma unroll
            for (int rr = 0; rr < 3; ++rr) {
                const float* row = &buf[(lr+rr)*K4_ROWSTRIDE + 4 + cc];
                float4 m = *(const float4*)row;
                float l = row[-1], r = row[4];
                float w0 = w9[rr*3+0], w1 = w9[rr*3+1], w2 = w9[rr*3+2];
                a0 = fmaf(w0,l,   fmaf(w1,m.x, fmaf(w2,m.y, a0)));
                a1 = fmaf(w0,m.x, fmaf(w1,m.y, fmaf(w2,m.z, a1)));
                a2 = fmaf(w0,m.y, fmaf(w1,m.z, fmaf(w2,m.w, a2)));
                a3 = fmaf(w0,m.z, fmaf(w1,m.w, fmaf(w2,r,   a3)));
            }
            out[g*4+0]=a0; out[g*4+1]=a1; out[g*4+2]=a2; out[g*4+3]=a3;
        }
    };

    float dq[8][8];
    float S[64];
    #pragma unroll
    for (int i = 0; i < 64; ++i) S[i] = 0.f;
    float sk[8];

    issue_loads(h*8 + 0);   // first q channel

    // ---- Q channels
    #pragma unroll
    for (int ch = 0; ch < 8; ++ch) {
        float* buf = sh + (ch & 1)*K4_BUF;
        write_lds(buf);
        issue_loads(ch < 7 ? (h*8 + ch + 1) : (64 + h*8));
        __syncthreads();
        conv8(buf, dww + (h*8 + ch)*9, dq[ch]);
    }

    // ---- K channels
    #pragma unroll
    for (int ch = 0; ch < 8; ++ch) {
        float* buf = sh + (ch & 1)*K4_BUF;
        write_lds(buf);
        issue_loads(ch < 7 ? (64 + h*8 + ch + 1) : (128 + h*8));
        __syncthreads();
        float dk[8];
        conv8(buf, dww + (64 + h*8 + ch)*9, dk);
        float s2 = 0.f;
        #pragma unroll
        for (int p = 0; p < 8; ++p) s2 += dk[p]*dk[p];
        sk[ch] = s2;
        #pragma unroll
        for (int c = 0; c < 8; ++c) {
            float acc = S[c*8 + ch];
            #pragma unroll
            for (int p = 0; p < 8; ++p) acc = fmaf(dq[c][p], dk[p], acc);
            S[c*8 + ch] = acc;
        }
    }

    // ---- V channels (compute + store only)
    #pragma unroll
    for (int ch = 0; ch < 8; ++ch) {
        float* buf = sh + (ch & 1)*K4_BUF;
        write_lds(buf);
        if (ch < 7) issue_loads(128 + h*8 + ch + 1);
        __syncthreads();
        float dv[8];
        conv8(buf, dww + (128 + h*8 + ch)*9, dv);
        float* vb = v + (size_t)(b*64 + h*8 + ch)*HWN + (r0 + lr)*256;
        *(float4*)&vb[c0]       = make_float4(dv[0],dv[1],dv[2],dv[3]);
        *(float4*)&vb[c0 + 128] = make_float4(dv[4],dv[5],dv[6],dv[7]);
    }

    // ---- reductions
    const int lane = t & 63;
    #pragma unroll
    for (int i = 0; i < 64; ++i) {
        float val = S[i];
        val += __shfl_xor(val,1);  val += __shfl_xor(val,2);  val += __shfl_xor(val,4);
        val += __shfl_xor(val,8);  val += __shfl_xor(val,16); val += __shfl_xor(val,32);
        if (lane == 0) atomicAdd(&Sg[(b*8+h)*64 + i], val);
    }
    #pragma unroll
    for (int c = 0; c < 8; ++c) {
        float v1 = 0.f;
        #pragma unroll
        for (int p = 0; p < 8; ++p) v1 += dq[c][p]*dq[c][p];
        float v2 = sk[c];
        v1 += __shfl_xor(v1,1);  v1 += __shfl_xor(v1,2);  v1 += __shfl_xor(v1,4);
        v1 += __shfl_xor(v1,8);  v1 += __shfl_xor(v1,16); v1 += __shfl_xor(v1,32);
        v2 += __shfl_xor(v2,1);  v2 += __shfl_xor(v2,2);  v2 += __shfl_xor(v2,4);
        v2 += __shfl_xor(v2,8);  v2 += __shfl_xor(v2,16); v2 += __shfl_xor(v2,32);
        if (lane == 0) {
            atomicAdd(&sumsq[b*128 + h*8 + c], v1);
            atomicAdd(&sumsq[b*128 + 64 + h*8 + c], v2);
        }
    }
}

// ---------------------------------------------------------------------------
// K6: finalize attention weights and thr. single block.
// ---------------------------------------------------------------------------
__global__ void k6_attn(const float* __restrict__ Sg, const float* __restrict__ sumsq,
                        const float* __restrict__ temp, const float* __restrict__ kdynp,
                        const float* __restrict__ thr_sum, const float* __restrict__ scales,
                        float* __restrict__ A, float* __restrict__ thr)
{
    const int t = threadIdx.x;
    if (t < 32) thr[t] = thr_sum[t] * (1.0f/(8.0f*65536.0f));
    const int b = t >> 6, h = (t >> 3) & 7, c = t & 7;
    const float kd = *kdynp;
    const float ssum = scales[0]+scales[1]+scales[2]+scales[3];
    const float nq = fmaxf(sqrtf(sumsq[b*128 + h*8 + c]), 1e-12f);
    const float tv = temp[h];
    const float* Srow = Sg + (size_t)(b*8+h)*64 + c*8;
    float a[8];
    #pragma unroll
    for (int d = 0; d < 8; ++d) {
        float nk = fmaxf(sqrtf(sumsq[b*128 + 64 + h*8 + d]), 1e-12f);
        a[d] = Srow[d] / (nq*nk) * tv;
    }
    bool keep[8];
    #pragma unroll
    for (int d = 0; d < 8; ++d) {
        int r = 0;
        #pragma unroll
        for (int e = 0; e < 8; ++e)
            r += (a[e] > a[d]) || (a[e] == a[d] && e < d);
        keep[d] = ((float)r < kd);
    }
    float m = -INFINITY;
    #pragma unroll
    for (int d = 0; d < 8; ++d) if (keep[d]) m = fmaxf(m, a[d]);
    float ex[8]; float sum = 0.f;
    #pragma unroll
    for (int d = 0; d < 8; ++d) { ex[d] = keep[d] ? expf(a[d]-m) : 0.f; sum += ex[d]; }
    const float inv = ssum / sum;
    #pragma unroll
    for (int d = 0; d < 8; ++d)
        A[(size_t)(b*8+h)*64 + c*8 + d] = ex[d]*inv;
}

// ---------------------------------------------------------------------------
// K7: mask path + post conv + residual + attn@v + proj_out, fused epilogue.
// ---------------------------------------------------------------------------
__global__ __launch_bounds__(256,2) void k7_final(
    const float* __restrict__ pre, const float* __restrict__ lb, const float* __restrict__ v,
    const float* __restrict__ cw,  const float* __restrict__ thr,
    const float* __restrict__ sw,  const float* __restrict__ sb,
    const float* __restrict__ A,
    const float* __restrict__ Wpost, const float* __restrict__ bpost,
    const float* __restrict__ Wout,  float* __restrict__ out)
{
    __shared__ float pr[64*64];
    __shared__ float vt[64*64];
    __shared__ float ft[128*64];
    float4* pr4 = (float4*)pr;
    float4* vt4 = (float4*)vt;
    float4* ft4 = (float4*)ft;

    const int t   = threadIdx.x;
    const int blk = blockIdx.x;
    const int b   = blk >> 10;
    const int p0  = (blk & 1023) << 6;
    const int pg  = t & 15;
    const int og  = t >> 4;

    const float4* pre4g = (const float4*)pre;
    const float4* v4g   = (const float4*)v;
    #pragma unroll
    for (int i = 0; i < 4; ++i) {
        int idx = t + 256*i;
        int c = idx >> 4, q = idx & 15;
        size_t gi = (size_t)(b*64 + c)*16384 + (p0>>2) + q;
        pr4[c*16+q] = pre4g[gi];
        vt4[c*16+q] = v4g[gi];
    }
    __syncthreads();

    #pragma unroll
    for (int s = 0; s < 2; ++s) {
        int task = t + 256*s;
        int g = task >> 6, px = task & 63;
        float xc[8], xv[8];
        float spa = sb[g];
        #pragma unroll
        for (int c = 0; c < 8; ++c) {
            xv[c] = pr[(g*8+c)*64 + px];
            xc[c] = xv[c]*cw[b*64 + g*8 + c];
            spa += xc[c]*sw[g*8 + c];
        }
        float sp = sgm(spa);
        float th = thr[b*8 + g];
        #pragma unroll
        for (int c = 0; c < 8; ++c) {
            float resp = sgm(xc[c]*sp);
            float mask = resp > th ? 1.0f : resp;
            pr[(g*8+c)*64 + px] = xv[c]*mask;
        }
    }
    __syncthreads();

    {
        const int o0 = og*4;
        float acc[4][4];
        #pragma unroll
        for (int j=0;j<4;++j){acc[j][0]=0.f;acc[j][1]=0.f;acc[j][2]=0.f;acc[j][3]=0.f;}
        const float4* W4 = (const float4*)Wpost;
        for (int c = 0; c < 64; c += 4) {
            float4 x0 = pr4[(c+0)*16+pg];
            float4 x1 = pr4[(c+1)*16+pg];
            float4 x2 = pr4[(c+2)*16+pg];
            float4 x3 = pr4[(c+3)*16+pg];
            #pragma unroll
            for (int j=0;j<4;++j)
                fma4(acc[j], W4[(o0+j)*16 + (c>>2)], x0,x1,x2,x3);
        }
        const float4* lb4 = (const float4*)lb;
        #pragma unroll
        for (int j=0;j<4;++j){
            float bs = bpost[o0+j];
            float4 lv = lb4[(size_t)(b*64 + o0+j)*16384 + (p0>>2) + pg];
            ft4[(64+o0+j)*16 + pg] = make_float4(acc[j][0]+bs+lv.x, acc[j][1]+bs+lv.y,
                                                 acc[j][2]+bs+lv.z, acc[j][3]+bs+lv.w);
        }
    }

    {
        const int ch0 = og*4;
        #pragma unroll
        for (int j = 0; j < 4; ++j) {
            int ch = ch0 + j;
            int hh = ch >> 3, c = ch & 7;
            const float* Ar = A + (size_t)(b*8+hh)*64 + c*8;
            float4 acc = make_float4(0.f,0.f,0.f,0.f);
            #pragma unroll
            for (int d = 0; d < 8; ++d) {
                float av = Ar[d];
                float4 vv = vt4[(hh*8+d)*16 + pg];
                acc.x += av*vv.x; acc.y += av*vv.y; acc.z += av*vv.z; acc.w += av*vv.w;
            }
            ft4[ch*16 + pg] = acc;
        }
    }
    __syncthreads();

    {
        const int o0 = og*8;
        float acc[8][4];
        #pragma unroll
        for (int j=0;j<8;++j){acc[j][0]=0.f;acc[j][1]=0.f;acc[j][2]=0.f;acc[j][3]=0.f;}
        const float4* W4 = (const float4*)Wout;
        for (int c = 0; c < 128; c += 4) {
            float4 x0 = ft4[(c+0)*16+pg];
            float4 x1 = ft4[(c+1)*16+pg];
            float4 x2 = ft4[(c+2)*16+pg];
            float4 x3 = ft4[(c+3)*16+pg];
            #pragma unroll
            for (int j=0;j<8;++j)
                fma4(acc[j], W4[(o0+j)*32 + (c>>2)], x0,x1,x2,x3);
        }
        float4* out4 = (float4*)out;
        #pragma unroll
        for (int j=0;j<8;++j)
            out4[(size_t)(b*128 + o0+j)*16384 + (p0>>2) + pg] =
                make_float4(acc[j][0],acc[j][1],acc[j][2],acc[j][3]);
    }
}

// ---------------------------------------------------------------------------
extern "C" void kernel_launch(void* const* d_in, const int* in_sizes, int n_in,
                              void* d_out, int out_size, void* d_ws, size_t ws_size,
                              hipStream_t stream)
{
    const float* x     = (const float*)d_in[0];
    const float* Wp    = (const float*)d_in[1];
    const float* Wpre  = (const float*)d_in[2];
    const float* bpre  = (const float*)d_in[3];
    const float* w1    = (const float*)d_in[4];
    const float* b1    = (const float*)d_in[5];
    const float* w2    = (const float*)d_in[6];
    const float* b2    = (const float*)d_in[7];
    const float* sw    = (const float*)d_in[8];
    const float* sb    = (const float*)d_in[9];
    const float* Wpost = (const float*)d_in[10];
    const float* bpost = (const float*)d_in[11];
    const float* Wqkv  = (const float*)d_in[12];
    const float* dww   = (const float*)d_in[13];
    const float* Wg1   = (const float*)d_in[14];
    const float* bg1   = (const float*)d_in[15];
    const float* wg2   = (const float*)d_in[16];
    const float* bg2   = (const float*)d_in[17];
    const float* temp  = (const float*)d_in[18];
    const float* scales= (const float*)d_in[19];
    const float* Wout  = (const float*)d_in[20];
    float* out = (float*)d_out;

    float* ws = (float*)d_ws;
    float* pooled_part = ws;                 // 16384
    float* gate_part   = ws + 16384;         // 64
    float* thr_sum     = ws + 16448;         // 32
    float* sumsq       = ws + 16480;         // 512
    float* Sg          = ws + 16992;         // 2048
    float* cw          = ws + 19040;         // 256
    float* kdyn        = ws + 19296;         // 1
    float* thr         = ws + 19328;         // 32
    float* A           = ws + 19360;         // 2048

    float* lb  = ws + 32768;
    float* pre = lb  + 16777216;
    float* qkv = pre + 16777216;
    float* v   = qkv + 50331648;

    hipMemsetAsync(ws, 0, (size_t)19040*sizeof(float), stream);

    k1_proj <<<4096, 256, 0, stream>>>(x, Wp, Wpre, bpre, Wqkv, Wg1, bg1, wg2, bg2,
                                       lb, pre, qkv, pooled_part, gate_part);
    k2_small<<<1,    256, 0, stream>>>(pooled_part, gate_part, w1, b1, w2, b2, cw, kdyn);
    k3_thr  <<<1024, 256, 0, stream>>>(pre, cw, sw, sb, thr_sum);
    k4_dw   <<<1024, 256, 0, stream>>>(qkv, dww, v, Sg, sumsq);
    k6_attn <<<1,    256, 0, stream>>>(Sg, sumsq, temp, kdyn, thr_sum, scales, A, thr);
    k7_final<<<4096, 256, 0, stream>>>(pre, lb, v, cw, thr, sw, sb, A,
                                       Wpost, bpost, Wout, out);
}